// Round 5
// baseline (413.381 us; speedup 1.0000x reference)
//
#include <hip/hip_runtime.h>
#include <math.h>

#define N_NODES 50000
#define N_EDGES 800000
#define NGRAPH  1024
#define IN_DIM  25
#define DIM     64

__device__ inline float wsum(float v) {
#pragma unroll
  for (int off = 32; off > 0; off >>= 1) v += __shfl_xor(v, off, 64);
  return v;
}
__device__ inline float sigmoidf(float x) { return 1.f / (1.f + expf(-x)); }

// ---------------- lin0 + relu + @Wc fused: weights in registers ----------
// lane = output dim. Each wave processes 8 rows with 8 independent chains.
__global__ __launch_bounds__(256) void k_lin0(const float* __restrict__ x,
    const float* __restrict__ W0, const float* __restrict__ b0,
    const float* __restrict__ Wc, float* __restrict__ hw) {
  int t = threadIdx.x, wave = t >> 6, lane = t & 63;
  float w0[IN_DIM], wc[DIM];
#pragma unroll
  for (int k = 0; k < IN_DIM; k++) w0[k] = W0[k * DIM + lane];
#pragma unroll
  for (int k = 0; k < DIM; k++) wc[k] = Wc[k * DIM + lane];
  float bb = b0[lane];
  int row0 = (blockIdx.x * 4 + wave) * 8;
  float xv[8], hreg[8], o[8];
#pragma unroll
  for (int r = 0; r < 8; r++) {
    int row = row0 + r;
    xv[r] = (row < N_NODES && lane < IN_DIM) ? x[row * IN_DIM + lane] : 0.f;
    hreg[r] = bb;
    o[r] = 0.f;
  }
#pragma unroll
  for (int k = 0; k < IN_DIM; k++) {
#pragma unroll
    for (int r = 0; r < 8; r++) hreg[r] += __shfl(xv[r], k, 64) * w0[k];
  }
#pragma unroll
  for (int r = 0; r < 8; r++) hreg[r] = fmaxf(hreg[r], 0.f);
#pragma unroll
  for (int k = 0; k < DIM; k++) {
#pragma unroll
    for (int r = 0; r < 8; r++) o[r] += __shfl(hreg[r], k, 64) * wc[k];
  }
#pragma unroll
  for (int r = 0; r < 8; r++) {
    int row = row0 + r;
    if (row < N_NODES) hw[(size_t)row * DIM + lane] = o[r];
  }
}

// ---------------- CSR build: count incoming edges per node ----------------
__global__ void k_count(const int* __restrict__ ei, int* __restrict__ cnt) {
  int e = blockIdx.x * blockDim.x + threadIdx.x;
  if (e < N_EDGES) atomicAdd(&cnt[ei[N_EDGES + e]], 1);
}

// ---------------- CSR build: single-block exclusive scan ----------------
__global__ __launch_bounds__(1024) void k_scan(int* __restrict__ cnt,
                                               float* __restrict__ dinv) {
  __shared__ int wsums[16];
  __shared__ int carry;
  int t = threadIdx.x, lane = t & 63, w = t >> 6;
  if (t == 0) carry = 0;
  __syncthreads();
  for (int base = 0; base < N_NODES; base += 8192) {
    int i0 = base + t * 8;
    int v[8];
    int local = 0;
#pragma unroll
    for (int k = 0; k < 8; k++) {
      int i = i0 + k;
      v[k] = (i < N_NODES) ? cnt[i] : 0;
      local += v[k];
    }
    int x = local;
#pragma unroll
    for (int d = 1; d < 64; d <<= 1) {
      int y = __shfl_up(x, d, 64);
      if (lane >= d) x += y;
    }
    if (lane == 63) wsums[w] = x;
    __syncthreads();
    if (t < 16) {
      int y = wsums[t];
#pragma unroll
      for (int d = 1; d < 16; d <<= 1) {
        int z = __shfl_up(y, d, 64);
        if (t >= d) y += z;
      }
      wsums[t] = y;
    }
    __syncthreads();
    int excl = x - local + ((w > 0) ? wsums[w - 1] : 0) + carry;
#pragma unroll
    for (int k = 0; k < 8; k++) {
      int i = i0 + k;
      if (i < N_NODES) {
        cnt[i] = excl;
        dinv[i] = rsqrtf((float)(v[k] + 1));
        excl += v[k];
      }
    }
    __syncthreads();
    if (t == 0) carry += wsums[15];
    __syncthreads();
  }
}

// ---------------- CSR build: fill adjacency (by destination) ----------------
__global__ void k_fill(const int* __restrict__ ei, int* __restrict__ cursor,
                       int* __restrict__ adj) {
  int e = blockIdx.x * blockDim.x + threadIdx.x;
  if (e < N_EDGES) {
    int row = ei[e];
    int col = ei[N_EDGES + e];
    int slot = atomicAdd(&cursor[col], 1);
    adj[slot] = row;
  }
}

// ---------------- weight transpose: WT[k][t], k<128: Wih, else Whh --------
__global__ __launch_bounds__(256) void k_wt(const float* __restrict__ Wih,
    const float* __restrict__ Whh, float* __restrict__ WT) {
  int k = blockIdx.x, t = threadIdx.x;
  float v = (k < 2 * DIM) ? Wih[t * 2 * DIM + k] : Whh[t * DIM + (k - 2 * DIM)];
  WT[k * 4 * DIM + t] = v;
}

// ---------------- GCN aggregate: gather per node (one wave per node) ------
__global__ __launch_bounds__(256) void k_gather(const int* __restrict__ adj,
    const int* __restrict__ cursor, const float* __restrict__ hw,
    const float* __restrict__ dinv, const float* __restrict__ bc,
    float* __restrict__ h) {
  int node = blockIdx.x * 4 + (threadIdx.x >> 6);
  int lane = threadIdx.x & 63;
  if (node >= N_NODES) return;
  int eend = cursor[node];
  int s = (node == 0) ? 0 : cursor[node - 1];
  float di = dinv[node];
  float acc = di * hw[(size_t)node * DIM + lane];  // self loop
  for (int cb = s; cb < eend; cb += 64) {
    int cn = min(64, eend - cb);
    int idx = (lane < cn) ? adj[cb + lane] : 0;
    float dv = (lane < cn) ? dinv[idx] : 0.f;
    float a0 = 0.f, a1 = 0.f, a2 = 0.f, a3 = 0.f;
    float a4 = 0.f, a5 = 0.f, a6 = 0.f, a7 = 0.f;
    int j = 0;
    for (; j + 8 <= cn; j += 8) {
      int r0 = __shfl(idx, j, 64), r1 = __shfl(idx, j + 1, 64);
      int r2 = __shfl(idx, j + 2, 64), r3 = __shfl(idx, j + 3, 64);
      int r4 = __shfl(idx, j + 4, 64), r5 = __shfl(idx, j + 5, 64);
      int r6 = __shfl(idx, j + 6, 64), r7 = __shfl(idx, j + 7, 64);
      float d0 = __shfl(dv, j, 64), d1 = __shfl(dv, j + 1, 64);
      float d2 = __shfl(dv, j + 2, 64), d3 = __shfl(dv, j + 3, 64);
      float d4 = __shfl(dv, j + 4, 64), d5 = __shfl(dv, j + 5, 64);
      float d6 = __shfl(dv, j + 6, 64), d7 = __shfl(dv, j + 7, 64);
      a0 += d0 * hw[(size_t)r0 * DIM + lane];
      a1 += d1 * hw[(size_t)r1 * DIM + lane];
      a2 += d2 * hw[(size_t)r2 * DIM + lane];
      a3 += d3 * hw[(size_t)r3 * DIM + lane];
      a4 += d4 * hw[(size_t)r4 * DIM + lane];
      a5 += d5 * hw[(size_t)r5 * DIM + lane];
      a6 += d6 * hw[(size_t)r6 * DIM + lane];
      a7 += d7 * hw[(size_t)r7 * DIM + lane];
    }
    for (; j < cn; j++) {
      int r = __shfl(idx, j, 64);
      float dr = __shfl(dv, j, 64);
      a0 += dr * hw[(size_t)r * DIM + lane];
    }
    acc += ((a0 + a1) + (a2 + a3)) + ((a4 + a5) + (a6 + a7));
  }
  h[(size_t)node * DIM + lane] = fmaxf(acc * di + bc[lane], 0.f);
}

// ---------------- fused Set2Set: 3x(LSTM + segment-softmax) + MLP head ----
__global__ __launch_bounds__(256) void k_set2set(
    const float* __restrict__ h, const int* __restrict__ batch,
    const float* __restrict__ WT, const float* __restrict__ bih,
    const float* __restrict__ bhh, const float* __restrict__ W1,
    const float* __restrict__ b1, const float* __restrict__ W2,
    const float* __restrict__ b2, float* __restrict__ out) {
  int b = blockIdx.x, t = threadIdx.x;
  int wave = t >> 6, lane = t & 63;
  __shared__ float qs[2 * DIM];
  __shared__ float hsl[DIM], csl[DIM];
  __shared__ float gates[4 * DIM];
  __shared__ float e_s[256];
  __shared__ float red[4 * DIM];
  __shared__ float lred[4], wmax[4];
  __shared__ int seg[2];
  if (t < 2) {  // graph boundary via binary search on sorted batch
    int g = b + t;
    int lo = 0, hi = N_NODES;
    if (g == NGRAPH) lo = N_NODES;
    else while (lo < hi) { int mid = (lo + hi) >> 1; if (batch[mid] < g) lo = mid + 1; else hi = mid; }
    seg[t] = lo;
  }
  if (t < 2 * DIM) qs[t] = 0.f;
  if (t < DIM) { hsl[t] = 0.f; csl[t] = 0.f; }
  __syncthreads();
  int s = seg[0], eend = seg[1];
  float bsum = bih[t] + bhh[t];
  for (int step = 0; step < 3; step++) {
    // ---- LSTM cell: thread t computes gate t (coalesced WT reads) ----
    float g = bsum;
    if (step > 0) {  // step 0: q_star = hs = 0 -> matmul contributes nothing
      const float* wp = WT + t;
      float g1 = 0.f;
#pragma unroll 8
      for (int k = 0; k < 2 * DIM; k += 2) {
        g += qs[k] * wp[k * 4 * DIM];
        g1 += qs[k + 1] * wp[(k + 1) * 4 * DIM];
      }
#pragma unroll 8
      for (int k = 0; k < DIM; k += 2) {
        g += hsl[k] * wp[(2 * DIM + k) * 4 * DIM];
        g1 += hsl[k + 1] * wp[(2 * DIM + k + 1) * 4 * DIM];
      }
      g += g1;
    }
    gates[t] = g;
    __syncthreads();
    if (t < DIM) {
      float ig = sigmoidf(gates[t]);
      float fg = sigmoidf(gates[DIM + t]);
      float gg = tanhf(gates[2 * DIM + t]);
      float og = sigmoidf(gates[3 * DIM + t]);
      float c = fg * csl[t] + ig * gg;
      csl[t] = c;
      float hh = og * tanhf(c);
      hsl[t] = hh;
      qs[t] = hh;  // q half of q_star
    }
    __syncthreads();
    // ---- segment softmax attention (online, chunked) ----
    float m_run = -INFINITY, l_w = 0.f, racc = 0.f;
    for (int cb = s; cb < eend; cb += 256) {
      int cn = min(256, eend - cb);
      for (int j = wave; j < cn; j += 4) {
        float p = h[(size_t)(cb + j) * DIM + lane] * hsl[lane];
        p = wsum(p);
        if (lane == 0) e_s[j] = p;
      }
      __syncthreads();
      float mv = (t < cn) ? e_s[t] : -INFINITY;
#pragma unroll
      for (int off = 32; off > 0; off >>= 1) mv = fmaxf(mv, __shfl_xor(mv, off, 64));
      if (lane == 0) wmax[wave] = mv;
      __syncthreads();
      float m_c = fmaxf(fmaxf(wmax[0], wmax[1]), fmaxf(wmax[2], wmax[3]));
      float m_new = fmaxf(m_run, m_c);
      float scale = expf(m_run - m_new);
      racc *= scale;
      l_w *= scale;
      m_run = m_new;
      for (int j = wave; j < cn; j += 4) {
        float a = expf(e_s[j] - m_run);
        l_w += a;  // lane-uniform within wave
        racc += a * h[(size_t)(cb + j) * DIM + lane];
      }
      __syncthreads();
    }
    red[wave * DIM + lane] = racc;
    if (lane == 0) lred[wave] = l_w;
    __syncthreads();
    if (t < DIM) {
      float r = red[t] + red[DIM + t] + red[2 * DIM + t] + red[3 * DIM + t];
      float l = lred[0] + lred[1] + lred[2] + lred[3];
      qs[DIM + t] = (l > 0.f) ? r / l : 0.f;
    }
    __syncthreads();
  }
  // ---- output MLP head ----
  if (t < DIM) {
    float acc = b1[t];
#pragma unroll
    for (int k = 0; k < 2 * DIM; k++) acc += qs[k] * W1[k * DIM + t];
    acc = fmaxf(acc, 0.f);
    float v = wsum(acc * W2[t]);
    if (t == 0) out[b] = v + b2[0];
  }
}

extern "C" void kernel_launch(void* const* d_in, const int* in_sizes, int n_in,
                              void* d_out, int out_size, void* d_ws, size_t ws_size,
                              hipStream_t stream) {
  const float* x    = (const float*)d_in[0];
  const int*   ei   = (const int*)d_in[1];
  const int*   batch= (const int*)d_in[2];
  const float* W0   = (const float*)d_in[3];
  const float* b0   = (const float*)d_in[4];
  const float* Wc   = (const float*)d_in[5];
  const float* bc   = (const float*)d_in[6];
  const float* Wih  = (const float*)d_in[7];
  const float* Whh  = (const float*)d_in[8];
  const float* bih  = (const float*)d_in[9];
  const float* bhh  = (const float*)d_in[10];
  const float* W1   = (const float*)d_in[11];
  const float* b1   = (const float*)d_in[12];
  const float* W2   = (const float*)d_in[13];
  const float* b2   = (const float*)d_in[14];
  float* out = (float*)d_out;

  float* ws   = (float*)d_ws;
  float* hw   = ws;                              // N*DIM
  float* h    = hw + (size_t)N_NODES * DIM;      // N*DIM
  float* dinv = h + (size_t)N_NODES * DIM;       // N
  float* WT   = dinv + N_NODES;                  // 192*256
  int* cnt    = (int*)(WT + 3 * DIM * 4 * DIM);  // N (count -> cursor -> end-offsets)
  int* adj    = cnt + N_NODES;                   // N_EDGES

  k_lin0<<<(N_NODES + 31) / 32, 256, 0, stream>>>(x, W0, b0, Wc, hw);
  hipMemsetAsync(cnt, 0, N_NODES * sizeof(int), stream);
  k_count<<<(N_EDGES + 255) / 256, 256, 0, stream>>>(ei, cnt);
  k_scan<<<1, 1024, 0, stream>>>(cnt, dinv);
  k_fill<<<(N_EDGES + 255) / 256, 256, 0, stream>>>(ei, cnt, adj);
  k_wt<<<3 * DIM, 256, 0, stream>>>(Wih, Whh, WT);
  k_gather<<<(N_NODES + 3) / 4, 256, 0, stream>>>(adj, cnt, hw, dinv, bc, h);
  k_set2set<<<NGRAPH, 256, 0, stream>>>(h, batch, WT, bih, bhh, W1, b1, W2, b2, out);
}

// Round 6
// 290.706 us; speedup vs baseline: 1.4220x; 1.4220x over previous
//
#include <hip/hip_runtime.h>
#include <math.h>

#define N_NODES 50000
#define N_EDGES 800000
#define NGRAPH  1024
#define IN_DIM  25
#define DIM     64

__device__ inline float wsum(float v) {
#pragma unroll
  for (int off = 32; off > 0; off >>= 1) v += __shfl_xor(v, off, 64);
  return v;
}
__device__ inline float sigmoidf(float x) { return 1.f / (1.f + expf(-x)); }

// ---------------- lin0 + relu + @Wc fused: LDS-tiled GEMM ----------------
// One block = 64 rows. Thread t owns a 4x4 output tile. Wave w owns rows
// 16w..16w+15 in both phases. A-operand LDS reads are 16-lane broadcasts.
__global__ __launch_bounds__(256) void k_lin0(const float* __restrict__ x,
    const float* __restrict__ W0, const float* __restrict__ b0,
    const float* __restrict__ Wc, float* __restrict__ hw) {
  __shared__ float sx[64][IN_DIM + 1];   // 64 x 26
  __shared__ float sW0[IN_DIM][DIM];
  __shared__ float sh[64][DIM + 4];      // relu(x@W0+b0)
  __shared__ float sWc[DIM][DIM];
  int t = threadIdx.x;
  int row0 = blockIdx.x * 64;
  for (int i = t; i < 64 * IN_DIM; i += 256) {
    int r = i / IN_DIM, k = i - r * IN_DIM;
    int row = row0 + r;
    sx[r][k] = (row < N_NODES) ? x[row * IN_DIM + k] : 0.f;
  }
  for (int i = t; i < IN_DIM * DIM; i += 256) sW0[i >> 6][i & 63] = W0[i];
  for (int i = t; i < DIM * DIM; i += 256) sWc[i >> 6][i & 63] = Wc[i];
  __syncthreads();
  int tc = (t & 15) * 4;   // output cols tc..tc+3
  int tr = (t >> 4) * 4;   // output rows tr..tr+3 (wave-local rows)
  float acc[4][4];
  {
    float4 bb = *(const float4*)&b0[tc];
#pragma unroll
    for (int i = 0; i < 4; i++) {
      acc[i][0] = bb.x; acc[i][1] = bb.y; acc[i][2] = bb.z; acc[i][3] = bb.w;
    }
  }
#pragma unroll
  for (int k = 0; k < IN_DIM; k++) {
    float4 w = *(const float4*)&sW0[k][tc];
#pragma unroll
    for (int i = 0; i < 4; i++) {
      float a = sx[tr + i][k];
      acc[i][0] += a * w.x; acc[i][1] += a * w.y;
      acc[i][2] += a * w.z; acc[i][3] += a * w.w;
    }
  }
#pragma unroll
  for (int i = 0; i < 4; i++) {
    sh[tr + i][tc + 0] = fmaxf(acc[i][0], 0.f);
    sh[tr + i][tc + 1] = fmaxf(acc[i][1], 0.f);
    sh[tr + i][tc + 2] = fmaxf(acc[i][2], 0.f);
    sh[tr + i][tc + 3] = fmaxf(acc[i][3], 0.f);
  }
  __syncthreads();
#pragma unroll
  for (int i = 0; i < 4; i++) acc[i][0] = acc[i][1] = acc[i][2] = acc[i][3] = 0.f;
#pragma unroll 8
  for (int k = 0; k < DIM; k++) {
    float4 w = *(const float4*)&sWc[k][tc];
#pragma unroll
    for (int i = 0; i < 4; i++) {
      float a = sh[tr + i][k];
      acc[i][0] += a * w.x; acc[i][1] += a * w.y;
      acc[i][2] += a * w.z; acc[i][3] += a * w.w;
    }
  }
#pragma unroll
  for (int i = 0; i < 4; i++) {
    int row = row0 + tr + i;
    if (row < N_NODES)
      *(float4*)&hw[(size_t)row * DIM + tc] =
          make_float4(acc[i][0], acc[i][1], acc[i][2], acc[i][3]);
  }
}

// ---------------- CSR build: count incoming edges per node ----------------
__global__ void k_count(const int* __restrict__ ei, int* __restrict__ cnt) {
  int e = blockIdx.x * blockDim.x + threadIdx.x;
  if (e < N_EDGES) atomicAdd(&cnt[ei[N_EDGES + e]], 1);
}

// ---------------- CSR build: single-block exclusive scan ----------------
__global__ __launch_bounds__(1024) void k_scan(int* __restrict__ cnt,
                                               float* __restrict__ dinv) {
  __shared__ int wsums[16];
  __shared__ int carry;
  int t = threadIdx.x, lane = t & 63, w = t >> 6;
  if (t == 0) carry = 0;
  __syncthreads();
  for (int base = 0; base < N_NODES; base += 8192) {
    int i0 = base + t * 8;
    int v[8];
    int local = 0;
#pragma unroll
    for (int k = 0; k < 8; k++) {
      int i = i0 + k;
      v[k] = (i < N_NODES) ? cnt[i] : 0;
      local += v[k];
    }
    int x = local;
#pragma unroll
    for (int d = 1; d < 64; d <<= 1) {
      int y = __shfl_up(x, d, 64);
      if (lane >= d) x += y;
    }
    if (lane == 63) wsums[w] = x;
    __syncthreads();
    if (t < 16) {
      int y = wsums[t];
#pragma unroll
      for (int d = 1; d < 16; d <<= 1) {
        int z = __shfl_up(y, d, 64);
        if (t >= d) y += z;
      }
      wsums[t] = y;
    }
    __syncthreads();
    int excl = x - local + ((w > 0) ? wsums[w - 1] : 0) + carry;
#pragma unroll
    for (int k = 0; k < 8; k++) {
      int i = i0 + k;
      if (i < N_NODES) {
        cnt[i] = excl;
        dinv[i] = rsqrtf((float)(v[k] + 1));
        excl += v[k];
      }
    }
    __syncthreads();
    if (t == 0) carry += wsums[15];
    __syncthreads();
  }
}

// ---------------- CSR build: fill adjacency (by destination) ----------------
__global__ void k_fill(const int* __restrict__ ei, int* __restrict__ cursor,
                       int* __restrict__ adj) {
  int e = blockIdx.x * blockDim.x + threadIdx.x;
  if (e < N_EDGES) {
    int row = ei[e];
    int col = ei[N_EDGES + e];
    int slot = atomicAdd(&cursor[col], 1);
    adj[slot] = row;
  }
}

// ---------------- weight transpose: WT[k][t], k<128: Wih, else Whh --------
__global__ __launch_bounds__(256) void k_wt(const float* __restrict__ Wih,
    const float* __restrict__ Whh, float* __restrict__ WT) {
  int k = blockIdx.x, t = threadIdx.x;
  float v = (k < 2 * DIM) ? Wih[t * 2 * DIM + k] : Whh[t * DIM + (k - 2 * DIM)];
  WT[k * 4 * DIM + t] = v;
}

// ---------------- GCN aggregate: gather per node (one wave per node) ------
__global__ __launch_bounds__(256) void k_gather(const int* __restrict__ adj,
    const int* __restrict__ cursor, const float* __restrict__ hw,
    const float* __restrict__ dinv, const float* __restrict__ bc,
    float* __restrict__ h) {
  int node = blockIdx.x * 4 + (threadIdx.x >> 6);
  int lane = threadIdx.x & 63;
  if (node >= N_NODES) return;
  int eend = cursor[node];
  int s = (node == 0) ? 0 : cursor[node - 1];
  float di = dinv[node];
  float acc = di * hw[(size_t)node * DIM + lane];  // self loop
  for (int cb = s; cb < eend; cb += 64) {
    int cn = min(64, eend - cb);
    int idx = (lane < cn) ? adj[cb + lane] : 0;
    float dv = (lane < cn) ? dinv[idx] : 0.f;
    float a0 = 0.f, a1 = 0.f, a2 = 0.f, a3 = 0.f;
    float a4 = 0.f, a5 = 0.f, a6 = 0.f, a7 = 0.f;
    int j = 0;
    for (; j + 8 <= cn; j += 8) {
      int r0 = __shfl(idx, j, 64), r1 = __shfl(idx, j + 1, 64);
      int r2 = __shfl(idx, j + 2, 64), r3 = __shfl(idx, j + 3, 64);
      int r4 = __shfl(idx, j + 4, 64), r5 = __shfl(idx, j + 5, 64);
      int r6 = __shfl(idx, j + 6, 64), r7 = __shfl(idx, j + 7, 64);
      float d0 = __shfl(dv, j, 64), d1 = __shfl(dv, j + 1, 64);
      float d2 = __shfl(dv, j + 2, 64), d3 = __shfl(dv, j + 3, 64);
      float d4 = __shfl(dv, j + 4, 64), d5 = __shfl(dv, j + 5, 64);
      float d6 = __shfl(dv, j + 6, 64), d7 = __shfl(dv, j + 7, 64);
      a0 += d0 * hw[(size_t)r0 * DIM + lane];
      a1 += d1 * hw[(size_t)r1 * DIM + lane];
      a2 += d2 * hw[(size_t)r2 * DIM + lane];
      a3 += d3 * hw[(size_t)r3 * DIM + lane];
      a4 += d4 * hw[(size_t)r4 * DIM + lane];
      a5 += d5 * hw[(size_t)r5 * DIM + lane];
      a6 += d6 * hw[(size_t)r6 * DIM + lane];
      a7 += d7 * hw[(size_t)r7 * DIM + lane];
    }
    for (; j < cn; j++) {
      int r = __shfl(idx, j, 64);
      float dr = __shfl(dv, j, 64);
      a0 += dr * hw[(size_t)r * DIM + lane];
    }
    acc += ((a0 + a1) + (a2 + a3)) + ((a4 + a5) + (a6 + a7));
  }
  h[(size_t)node * DIM + lane] = fmaxf(acc * di + bc[lane], 0.f);
}

// ---------------- fused Set2Set: 3x(LSTM + segment-softmax) + MLP head ----
__global__ __launch_bounds__(256) void k_set2set(
    const float* __restrict__ h, const int* __restrict__ batch,
    const float* __restrict__ WT, const float* __restrict__ bih,
    const float* __restrict__ bhh, const float* __restrict__ W1,
    const float* __restrict__ b1, const float* __restrict__ W2,
    const float* __restrict__ b2, float* __restrict__ out) {
  int b = blockIdx.x, t = threadIdx.x;
  int wave = t >> 6, lane = t & 63;
  __shared__ float qs[2 * DIM];
  __shared__ float hsl[DIM], csl[DIM];
  __shared__ float gates[4 * DIM];
  __shared__ float e_s[256];
  __shared__ float red[4 * DIM];
  __shared__ float lred[4], wmax[4];
  __shared__ int seg[2];
  if (t < 2) {  // graph boundary via binary search on sorted batch
    int g = b + t;
    int lo = 0, hi = N_NODES;
    if (g == NGRAPH) lo = N_NODES;
    else while (lo < hi) { int mid = (lo + hi) >> 1; if (batch[mid] < g) lo = mid + 1; else hi = mid; }
    seg[t] = lo;
  }
  if (t < 2 * DIM) qs[t] = 0.f;
  if (t < DIM) { hsl[t] = 0.f; csl[t] = 0.f; }
  __syncthreads();
  int s = seg[0], eend = seg[1];
  float bsum = bih[t] + bhh[t];
  for (int step = 0; step < 3; step++) {
    // ---- LSTM cell: thread t computes gate t (coalesced WT reads) ----
    float g = bsum;
    if (step > 0) {  // step 0: q_star = hs = 0 -> matmul contributes nothing
      const float* wp = WT + t;
      float g1 = 0.f;
#pragma unroll 8
      for (int k = 0; k < 2 * DIM; k += 2) {
        g += qs[k] * wp[k * 4 * DIM];
        g1 += qs[k + 1] * wp[(k + 1) * 4 * DIM];
      }
#pragma unroll 8
      for (int k = 0; k < DIM; k += 2) {
        g += hsl[k] * wp[(2 * DIM + k) * 4 * DIM];
        g1 += hsl[k + 1] * wp[(2 * DIM + k + 1) * 4 * DIM];
      }
      g += g1;
    }
    gates[t] = g;
    __syncthreads();
    if (t < DIM) {
      float ig = sigmoidf(gates[t]);
      float fg = sigmoidf(gates[DIM + t]);
      float gg = tanhf(gates[2 * DIM + t]);
      float og = sigmoidf(gates[3 * DIM + t]);
      float c = fg * csl[t] + ig * gg;
      csl[t] = c;
      float hh = og * tanhf(c);
      hsl[t] = hh;
      qs[t] = hh;  // q half of q_star
    }
    __syncthreads();
    // ---- segment softmax attention (online, chunked) ----
    float m_run = -INFINITY, l_w = 0.f, racc = 0.f;
    for (int cb = s; cb < eend; cb += 256) {
      int cn = min(256, eend - cb);
      for (int j = wave; j < cn; j += 4) {
        float p = h[(size_t)(cb + j) * DIM + lane] * hsl[lane];
        p = wsum(p);
        if (lane == 0) e_s[j] = p;
      }
      __syncthreads();
      float mv = (t < cn) ? e_s[t] : -INFINITY;
#pragma unroll
      for (int off = 32; off > 0; off >>= 1) mv = fmaxf(mv, __shfl_xor(mv, off, 64));
      if (lane == 0) wmax[wave] = mv;
      __syncthreads();
      float m_c = fmaxf(fmaxf(wmax[0], wmax[1]), fmaxf(wmax[2], wmax[3]));
      float m_new = fmaxf(m_run, m_c);
      float scale = expf(m_run - m_new);
      racc *= scale;
      l_w *= scale;
      m_run = m_new;
      for (int j = wave; j < cn; j += 4) {
        float a = expf(e_s[j] - m_run);
        l_w += a;  // lane-uniform within wave
        racc += a * h[(size_t)(cb + j) * DIM + lane];
      }
      __syncthreads();
    }
    red[wave * DIM + lane] = racc;
    if (lane == 0) lred[wave] = l_w;
    __syncthreads();
    if (t < DIM) {
      float r = red[t] + red[DIM + t] + red[2 * DIM + t] + red[3 * DIM + t];
      float l = lred[0] + lred[1] + lred[2] + lred[3];
      qs[DIM + t] = (l > 0.f) ? r / l : 0.f;
    }
    __syncthreads();
  }
  // ---- output MLP head ----
  if (t < DIM) {
    float acc = b1[t];
#pragma unroll
    for (int k = 0; k < 2 * DIM; k++) acc += qs[k] * W1[k * DIM + t];
    acc = fmaxf(acc, 0.f);
    float v = wsum(acc * W2[t]);
    if (t == 0) out[b] = v + b2[0];
  }
}

extern "C" void kernel_launch(void* const* d_in, const int* in_sizes, int n_in,
                              void* d_out, int out_size, void* d_ws, size_t ws_size,
                              hipStream_t stream) {
  const float* x    = (const float*)d_in[0];
  const int*   ei   = (const int*)d_in[1];
  const int*   batch= (const int*)d_in[2];
  const float* W0   = (const float*)d_in[3];
  const float* b0   = (const float*)d_in[4];
  const float* Wc   = (const float*)d_in[5];
  const float* bc   = (const float*)d_in[6];
  const float* Wih  = (const float*)d_in[7];
  const float* Whh  = (const float*)d_in[8];
  const float* bih  = (const float*)d_in[9];
  const float* bhh  = (const float*)d_in[10];
  const float* W1   = (const float*)d_in[11];
  const float* b1   = (const float*)d_in[12];
  const float* W2   = (const float*)d_in[13];
  const float* b2   = (const float*)d_in[14];
  float* out = (float*)d_out;

  float* ws   = (float*)d_ws;
  float* hw   = ws;                              // N*DIM
  float* h    = hw + (size_t)N_NODES * DIM;      // N*DIM
  float* dinv = h + (size_t)N_NODES * DIM;       // N
  float* WT   = dinv + N_NODES;                  // 192*256
  int* cnt    = (int*)(WT + 3 * DIM * 4 * DIM);  // N (count -> cursor -> end-offsets)
  int* adj    = cnt + N_NODES;                   // N_EDGES

  k_lin0<<<(N_NODES + 63) / 64, 256, 0, stream>>>(x, W0, b0, Wc, hw);
  hipMemsetAsync(cnt, 0, N_NODES * sizeof(int), stream);
  k_count<<<(N_EDGES + 255) / 256, 256, 0, stream>>>(ei, cnt);
  k_scan<<<1, 1024, 0, stream>>>(cnt, dinv);
  k_fill<<<(N_EDGES + 255) / 256, 256, 0, stream>>>(ei, cnt, adj);
  k_wt<<<3 * DIM, 256, 0, stream>>>(Wih, Whh, WT);
  k_gather<<<(N_NODES + 3) / 4, 256, 0, stream>>>(adj, cnt, hw, dinv, bc, h);
  k_set2set<<<NGRAPH, 256, 0, stream>>>(h, batch, WT, bih, bhh, W1, b1, W2, b2, out);
}

// Round 7
// 267.739 us; speedup vs baseline: 1.5440x; 1.0858x over previous
//
#include <hip/hip_runtime.h>
#include <math.h>

#define N_NODES 50000
#define N_EDGES 800000
#define NGRAPH  1024
#define IN_DIM  25
#define DIM     64

// CSR binning params
#define NPB 512                    // nodes per bucket
#define NB  98                     // ceil(N_NODES / NPB)
#define CAP 12288                  // pairs capacity per bucket (mean 8192, sigma ~90)

__device__ inline float wsum(float v) {
#pragma unroll
  for (int off = 32; off > 0; off >>= 1) v += __shfl_xor(v, off, 64);
  return v;
}
__device__ inline float sigmoidf(float x) { return 1.f / (1.f + expf(-x)); }

// ---------------- lin0 + relu + @Wc fused: LDS-tiled GEMM ----------------
__global__ __launch_bounds__(256) void k_lin0(const float* __restrict__ x,
    const float* __restrict__ W0, const float* __restrict__ b0,
    const float* __restrict__ Wc, float* __restrict__ hw) {
  __shared__ float sx[64][IN_DIM + 1];
  __shared__ float sW0[IN_DIM][DIM];
  __shared__ float sh[64][DIM + 4];
  __shared__ float sWc[DIM][DIM];
  int t = threadIdx.x;
  int row0 = blockIdx.x * 64;
  for (int i = t; i < 64 * IN_DIM; i += 256) {
    int r = i / IN_DIM, k = i - r * IN_DIM;
    int row = row0 + r;
    sx[r][k] = (row < N_NODES) ? x[row * IN_DIM + k] : 0.f;
  }
  for (int i = t; i < IN_DIM * DIM; i += 256) sW0[i >> 6][i & 63] = W0[i];
  for (int i = t; i < DIM * DIM; i += 256) sWc[i >> 6][i & 63] = Wc[i];
  __syncthreads();
  int tc = (t & 15) * 4;
  int tr = (t >> 4) * 4;
  float acc[4][4];
  {
    float4 bb = *(const float4*)&b0[tc];
#pragma unroll
    for (int i = 0; i < 4; i++) {
      acc[i][0] = bb.x; acc[i][1] = bb.y; acc[i][2] = bb.z; acc[i][3] = bb.w;
    }
  }
#pragma unroll
  for (int k = 0; k < IN_DIM; k++) {
    float4 w = *(const float4*)&sW0[k][tc];
#pragma unroll
    for (int i = 0; i < 4; i++) {
      float a = sx[tr + i][k];
      acc[i][0] += a * w.x; acc[i][1] += a * w.y;
      acc[i][2] += a * w.z; acc[i][3] += a * w.w;
    }
  }
#pragma unroll
  for (int i = 0; i < 4; i++) {
    sh[tr + i][tc + 0] = fmaxf(acc[i][0], 0.f);
    sh[tr + i][tc + 1] = fmaxf(acc[i][1], 0.f);
    sh[tr + i][tc + 2] = fmaxf(acc[i][2], 0.f);
    sh[tr + i][tc + 3] = fmaxf(acc[i][3], 0.f);
  }
  __syncthreads();
#pragma unroll
  for (int i = 0; i < 4; i++) acc[i][0] = acc[i][1] = acc[i][2] = acc[i][3] = 0.f;
#pragma unroll 8
  for (int k = 0; k < DIM; k++) {
    float4 w = *(const float4*)&sWc[k][tc];
#pragma unroll
    for (int i = 0; i < 4; i++) {
      float a = sh[tr + i][k];
      acc[i][0] += a * w.x; acc[i][1] += a * w.y;
      acc[i][2] += a * w.z; acc[i][3] += a * w.w;
    }
  }
#pragma unroll
  for (int i = 0; i < 4; i++) {
    int row = row0 + tr + i;
    if (row < N_NODES)
      *(float4*)&hw[(size_t)row * DIM + tc] =
          make_float4(acc[i][0], acc[i][1], acc[i][2], acc[i][3]);
  }
}

// ---------------- CSR: count incoming edges per node (+ init bucket cursors)
__global__ void k_count(const int* __restrict__ ei, int* __restrict__ cnt,
                        int* __restrict__ gcur) {
  if (blockIdx.x == 0 && threadIdx.x < NB) gcur[threadIdx.x] = threadIdx.x * CAP;
  int e = blockIdx.x * blockDim.x + threadIdx.x;
  if (e < N_EDGES) atomicAdd(&cnt[ei[N_EDGES + e]], 1);
}

// ---------------- CSR: single-block exclusive scan ------------------------
__global__ __launch_bounds__(1024) void k_scan(int* __restrict__ cnt,
                                               float* __restrict__ dinv) {
  __shared__ int wsums[16];
  __shared__ int carry;
  int t = threadIdx.x, lane = t & 63, w = t >> 6;
  if (t == 0) carry = 0;
  __syncthreads();
  for (int base = 0; base < N_NODES; base += 8192) {
    int i0 = base + t * 8;
    int v[8];
    int local = 0;
#pragma unroll
    for (int k = 0; k < 8; k++) {
      int i = i0 + k;
      v[k] = (i < N_NODES) ? cnt[i] : 0;
      local += v[k];
    }
    int x = local;
#pragma unroll
    for (int d = 1; d < 64; d <<= 1) {
      int y = __shfl_up(x, d, 64);
      if (lane >= d) x += y;
    }
    if (lane == 63) wsums[w] = x;
    __syncthreads();
    if (t < 16) {
      int y = wsums[t];
#pragma unroll
      for (int d = 1; d < 16; d <<= 1) {
        int z = __shfl_up(y, d, 64);
        if (t >= d) y += z;
      }
      wsums[t] = y;
    }
    __syncthreads();
    int excl = x - local + ((w > 0) ? wsums[w - 1] : 0) + carry;
#pragma unroll
    for (int k = 0; k < 8; k++) {
      int i = i0 + k;
      if (i < N_NODES) {
        cnt[i] = excl;
        dinv[i] = rsqrtf((float)(v[k] + 1));
        excl += v[k];
      }
    }
    __syncthreads();
    if (t == 0) carry += wsums[15];
    __syncthreads();
  }
  if (t == 0) cnt[N_NODES] = N_EDGES;  // sentinel
}

// ---------------- CSR pass 1: bin edges into NB coarse buckets ------------
// Chunk = 2048 edges/block. LDS ranks + one global atomic per bucket per
// block => (row,col) pairs written in sequential runs (L2 write-combined).
__global__ __launch_bounds__(256) void k_bin(const int* __restrict__ ei,
    int* __restrict__ gcur, uint2* __restrict__ pairs) {
  __shared__ int lcnt[NB];
  __shared__ int lbase[NB];
  int t = threadIdx.x;
  int base = blockIdx.x * 2048;
  for (int i = t; i < NB; i += 256) lcnt[i] = 0;
  __syncthreads();
  int rows[8], cols[8], rank[8];
#pragma unroll
  for (int k = 0; k < 8; k++) {
    int e = base + k * 256 + t;
    if (e < N_EDGES) {
      rows[k] = ei[e];
      cols[k] = ei[N_EDGES + e];
      rank[k] = atomicAdd(&lcnt[cols[k] >> 9], 1);
    } else {
      cols[k] = -1;
    }
  }
  __syncthreads();
  for (int i = t; i < NB; i += 256) lbase[i] = atomicAdd(&gcur[i], lcnt[i]);
  __syncthreads();
#pragma unroll
  for (int k = 0; k < 8; k++) {
    if (cols[k] >= 0) {
      int b = cols[k] >> 9;
      int pos = lbase[b] + rank[k];
      if (pos < (b + 1) * CAP)
        pairs[pos] = make_uint2((unsigned)rows[k], (unsigned)cols[k]);
    }
  }
}

// ---------------- CSR pass 2: per-bucket fill (LDS cursors, local writes) -
__global__ __launch_bounds__(256) void k_fill2(const uint2* __restrict__ pairs,
    const int* __restrict__ gcur, const int* __restrict__ cnt,
    int* __restrict__ adj) {
  __shared__ int lcur[NPB];
  int b = blockIdx.x, t = threadIdx.x;
  int nb0 = b * NPB;
  for (int i = t; i < NPB; i += 256) {
    int node = nb0 + i;
    lcur[i] = (node < N_NODES) ? cnt[node] : 0;
  }
  __syncthreads();
  int ne = gcur[b] - b * CAP;
  if (ne > CAP) ne = CAP;
  for (int i = t; i < ne; i += 256) {
    uint2 p = pairs[(size_t)b * CAP + i];
    int slot = atomicAdd(&lcur[p.y - nb0], 1);
    adj[slot] = (int)p.x;
  }
}

// ---------------- GCN aggregate: gather per node (one wave per node) ------
__global__ __launch_bounds__(256) void k_gather(const int* __restrict__ adj,
    const int* __restrict__ cnt, const float* __restrict__ hw,
    const float* __restrict__ dinv, const float* __restrict__ bc,
    float* __restrict__ h) {
  int node = blockIdx.x * 4 + (threadIdx.x >> 6);
  int lane = threadIdx.x & 63;
  if (node >= N_NODES) return;
  int s = cnt[node], eend = cnt[node + 1];
  float di = dinv[node];
  float acc = di * hw[(size_t)node * DIM + lane];  // self loop
  for (int cb = s; cb < eend; cb += 64) {
    int cn = min(64, eend - cb);
    int idx = (lane < cn) ? adj[cb + lane] : 0;
    float dv = (lane < cn) ? dinv[idx] : 0.f;
    float a0 = 0.f, a1 = 0.f, a2 = 0.f, a3 = 0.f;
    float a4 = 0.f, a5 = 0.f, a6 = 0.f, a7 = 0.f;
    int j = 0;
    for (; j + 8 <= cn; j += 8) {
      int r0 = __shfl(idx, j, 64), r1 = __shfl(idx, j + 1, 64);
      int r2 = __shfl(idx, j + 2, 64), r3 = __shfl(idx, j + 3, 64);
      int r4 = __shfl(idx, j + 4, 64), r5 = __shfl(idx, j + 5, 64);
      int r6 = __shfl(idx, j + 6, 64), r7 = __shfl(idx, j + 7, 64);
      float d0 = __shfl(dv, j, 64), d1 = __shfl(dv, j + 1, 64);
      float d2 = __shfl(dv, j + 2, 64), d3 = __shfl(dv, j + 3, 64);
      float d4 = __shfl(dv, j + 4, 64), d5 = __shfl(dv, j + 5, 64);
      float d6 = __shfl(dv, j + 6, 64), d7 = __shfl(dv, j + 7, 64);
      a0 += d0 * hw[(size_t)r0 * DIM + lane];
      a1 += d1 * hw[(size_t)r1 * DIM + lane];
      a2 += d2 * hw[(size_t)r2 * DIM + lane];
      a3 += d3 * hw[(size_t)r3 * DIM + lane];
      a4 += d4 * hw[(size_t)r4 * DIM + lane];
      a5 += d5 * hw[(size_t)r5 * DIM + lane];
      a6 += d6 * hw[(size_t)r6 * DIM + lane];
      a7 += d7 * hw[(size_t)r7 * DIM + lane];
    }
    for (; j < cn; j++) {
      int r = __shfl(idx, j, 64);
      float dr = __shfl(dv, j, 64);
      a0 += dr * hw[(size_t)r * DIM + lane];
    }
    acc += ((a0 + a1) + (a2 + a3)) + ((a4 + a5) + (a6 + a7));
  }
  h[(size_t)node * DIM + lane] = fmaxf(acc * di + bc[lane], 0.f);
}

// ---------------- weight transpose: WT[k][t], k<128: Wih, else Whh --------
__global__ __launch_bounds__(256) void k_wt(const float* __restrict__ Wih,
    const float* __restrict__ Whh, float* __restrict__ WT) {
  int k = blockIdx.x, t = threadIdx.x;
  float v = (k < 2 * DIM) ? Wih[t * 2 * DIM + k] : Whh[t * DIM + (k - 2 * DIM)];
  WT[k * 4 * DIM + t] = v;
}

// ---------------- fused Set2Set: 3x(LSTM + segment-softmax) + MLP head ----
__global__ __launch_bounds__(256) void k_set2set(
    const float* __restrict__ h, const int* __restrict__ batch,
    const float* __restrict__ WT, const float* __restrict__ bih,
    const float* __restrict__ bhh, const float* __restrict__ W1,
    const float* __restrict__ b1, const float* __restrict__ W2,
    const float* __restrict__ b2, float* __restrict__ out) {
  int b = blockIdx.x, t = threadIdx.x;
  int wave = t >> 6, lane = t & 63;
  __shared__ float qs[2 * DIM];
  __shared__ float hsl[DIM], csl[DIM];
  __shared__ float gates[4 * DIM];
  __shared__ float e_s[256];
  __shared__ float red[4 * DIM];
  __shared__ float lred[4], wmax[4];
  __shared__ int seg[2];
  if (t < 2) {  // graph boundary via binary search on sorted batch
    int g = b + t;
    int lo = 0, hi = N_NODES;
    if (g == NGRAPH) lo = N_NODES;
    else while (lo < hi) { int mid = (lo + hi) >> 1; if (batch[mid] < g) lo = mid + 1; else hi = mid; }
    seg[t] = lo;
  }
  if (t < 2 * DIM) qs[t] = 0.f;
  if (t < DIM) { hsl[t] = 0.f; csl[t] = 0.f; }
  __syncthreads();
  int s = seg[0], eend = seg[1];
  float bsum = bih[t] + bhh[t];
  for (int step = 0; step < 3; step++) {
    float g = bsum;
    if (step > 0) {  // step 0: q_star = hs = 0 -> matmul contributes nothing
      const float* wp = WT + t;
      float g1 = 0.f;
#pragma unroll 8
      for (int k = 0; k < 2 * DIM; k += 2) {
        g += qs[k] * wp[k * 4 * DIM];
        g1 += qs[k + 1] * wp[(k + 1) * 4 * DIM];
      }
#pragma unroll 8
      for (int k = 0; k < DIM; k += 2) {
        g += hsl[k] * wp[(2 * DIM + k) * 4 * DIM];
        g1 += hsl[k + 1] * wp[(2 * DIM + k + 1) * 4 * DIM];
      }
      g += g1;
    }
    gates[t] = g;
    __syncthreads();
    if (t < DIM) {
      float ig = sigmoidf(gates[t]);
      float fg = sigmoidf(gates[DIM + t]);
      float gg = tanhf(gates[2 * DIM + t]);
      float og = sigmoidf(gates[3 * DIM + t]);
      float c = fg * csl[t] + ig * gg;
      csl[t] = c;
      float hh = og * tanhf(c);
      hsl[t] = hh;
      qs[t] = hh;  // q half of q_star
    }
    __syncthreads();
    float m_run = -INFINITY, l_w = 0.f, racc = 0.f;
    for (int cb = s; cb < eend; cb += 256) {
      int cn = min(256, eend - cb);
      for (int j = wave; j < cn; j += 4) {
        float p = h[(size_t)(cb + j) * DIM + lane] * hsl[lane];
        p = wsum(p);
        if (lane == 0) e_s[j] = p;
      }
      __syncthreads();
      float mv = (t < cn) ? e_s[t] : -INFINITY;
#pragma unroll
      for (int off = 32; off > 0; off >>= 1) mv = fmaxf(mv, __shfl_xor(mv, off, 64));
      if (lane == 0) wmax[wave] = mv;
      __syncthreads();
      float m_c = fmaxf(fmaxf(wmax[0], wmax[1]), fmaxf(wmax[2], wmax[3]));
      float m_new = fmaxf(m_run, m_c);
      float scale = expf(m_run - m_new);
      racc *= scale;
      l_w *= scale;
      m_run = m_new;
      for (int j = wave; j < cn; j += 4) {
        float a = expf(e_s[j] - m_run);
        l_w += a;  // lane-uniform within wave
        racc += a * h[(size_t)(cb + j) * DIM + lane];
      }
      __syncthreads();
    }
    red[wave * DIM + lane] = racc;
    if (lane == 0) lred[wave] = l_w;
    __syncthreads();
    if (t < DIM) {
      float r = red[t] + red[DIM + t] + red[2 * DIM + t] + red[3 * DIM + t];
      float l = lred[0] + lred[1] + lred[2] + lred[3];
      qs[DIM + t] = (l > 0.f) ? r / l : 0.f;
    }
    __syncthreads();
  }
  if (t < DIM) {
    float acc = b1[t];
#pragma unroll
    for (int k = 0; k < 2 * DIM; k++) acc += qs[k] * W1[k * DIM + t];
    acc = fmaxf(acc, 0.f);
    float v = wsum(acc * W2[t]);
    if (t == 0) out[b] = v + b2[0];
  }
}

extern "C" void kernel_launch(void* const* d_in, const int* in_sizes, int n_in,
                              void* d_out, int out_size, void* d_ws, size_t ws_size,
                              hipStream_t stream) {
  const float* x    = (const float*)d_in[0];
  const int*   ei   = (const int*)d_in[1];
  const int*   batch= (const int*)d_in[2];
  const float* W0   = (const float*)d_in[3];
  const float* b0   = (const float*)d_in[4];
  const float* Wc   = (const float*)d_in[5];
  const float* bc   = (const float*)d_in[6];
  const float* Wih  = (const float*)d_in[7];
  const float* Whh  = (const float*)d_in[8];
  const float* bih  = (const float*)d_in[9];
  const float* bhh  = (const float*)d_in[10];
  const float* W1   = (const float*)d_in[11];
  const float* b1   = (const float*)d_in[12];
  const float* W2   = (const float*)d_in[13];
  const float* b2   = (const float*)d_in[14];
  float* out = (float*)d_out;

  float* ws   = (float*)d_ws;
  float* hw   = ws;                              // N*DIM
  float* h    = hw + (size_t)N_NODES * DIM;      // N*DIM
  float* dinv = h + (size_t)N_NODES * DIM;       // N
  float* WT   = dinv + N_NODES;                  // 192*256
  int* cnt    = (int*)(WT + 3 * DIM * 4 * DIM);  // N+2 (offsets + sentinel + pad)
  int* adj    = cnt + N_NODES + 2;               // N_EDGES
  int* gcur   = adj + N_EDGES;                   // NB bucket cursors
  // pad so pairs is 8-byte aligned: ints so far = 50002 + 800000 + 98 = 850100 (even)
  uint2* pairs = (uint2*)(gcur + NB);            // NB*CAP pairs (~9.6 MB)

  k_lin0<<<(N_NODES + 63) / 64, 256, 0, stream>>>(x, W0, b0, Wc, hw);
  hipMemsetAsync(cnt, 0, N_NODES * sizeof(int), stream);
  k_count<<<(N_EDGES + 255) / 256, 256, 0, stream>>>(ei, cnt, gcur);
  k_scan<<<1, 1024, 0, stream>>>(cnt, dinv);
  k_bin<<<(N_EDGES + 2047) / 2048, 256, 0, stream>>>(ei, gcur, pairs);
  k_fill2<<<NB, 256, 0, stream>>>(pairs, gcur, cnt, adj);
  k_wt<<<3 * DIM, 256, 0, stream>>>(Wih, Whh, WT);
  k_gather<<<(N_NODES + 3) / 4, 256, 0, stream>>>(adj, cnt, hw, dinv, bc, h);
  k_set2set<<<NGRAPH, 256, 0, stream>>>(h, batch, WT, bih, bhh, W1, b1, W2, b2, out);
}

// Round 8
// 263.649 us; speedup vs baseline: 1.5679x; 1.0155x over previous
//
#include <hip/hip_runtime.h>
#include <math.h>

#define N_NODES 50000
#define N_EDGES 800000
#define NGRAPH  1024
#define IN_DIM  25
#define DIM     64

// CSR binning params
#define NPB 512                    // nodes per bucket
#define NB  98                     // ceil(N_NODES / NPB)
#define CAP 12288                  // pairs capacity per bucket (mean 8192)

// fused lin0+count grid split
#define NLIN 782                   // ceil(N_NODES / 64)
#define NCNT 391                   // ceil(N_EDGES / 2048)

__device__ inline float wsum(float v) {
#pragma unroll
  for (int off = 32; off > 0; off >>= 1) v += __shfl_xor(v, off, 64);
  return v;
}
__device__ inline float sigmoidf(float x) { return 1.f / (1.f + expf(-x)); }

// ------- fused: lin0+relu+@Wc (blocks 0..NLIN-1)  |  edge count (rest) -----
__global__ __launch_bounds__(256) void k_lin0cnt(const float* __restrict__ x,
    const float* __restrict__ W0, const float* __restrict__ b0,
    const float* __restrict__ Wc, float* __restrict__ hw,
    const int* __restrict__ ei, int* __restrict__ cnt) {
  __shared__ float sx[64][IN_DIM + 1];
  __shared__ float sW0[IN_DIM][DIM];
  __shared__ float sh[64][DIM + 4];
  __shared__ float sWc[DIM][DIM];
  int t = threadIdx.x;
  if (blockIdx.x >= NLIN) {  // ---- count branch: 2048 edges per block ----
    int base = (blockIdx.x - NLIN) * 2048 + t;
#pragma unroll
    for (int k = 0; k < 8; k++) {
      int e = base + k * 256;
      if (e < N_EDGES) atomicAdd(&cnt[ei[N_EDGES + e]], 1);
    }
    return;
  }
  int row0 = blockIdx.x * 64;
  for (int i = t; i < 64 * IN_DIM; i += 256) {
    int r = i / IN_DIM, k = i - r * IN_DIM;
    int row = row0 + r;
    sx[r][k] = (row < N_NODES) ? x[row * IN_DIM + k] : 0.f;
  }
  for (int i = t; i < IN_DIM * DIM; i += 256) sW0[i >> 6][i & 63] = W0[i];
  for (int i = t; i < DIM * DIM; i += 256) sWc[i >> 6][i & 63] = Wc[i];
  __syncthreads();
  int tc = (t & 15) * 4;
  int tr = (t >> 4) * 4;
  float acc[4][4];
  {
    float4 bb = *(const float4*)&b0[tc];
#pragma unroll
    for (int i = 0; i < 4; i++) {
      acc[i][0] = bb.x; acc[i][1] = bb.y; acc[i][2] = bb.z; acc[i][3] = bb.w;
    }
  }
#pragma unroll
  for (int k = 0; k < IN_DIM; k++) {
    float4 w = *(const float4*)&sW0[k][tc];
#pragma unroll
    for (int i = 0; i < 4; i++) {
      float a = sx[tr + i][k];
      acc[i][0] += a * w.x; acc[i][1] += a * w.y;
      acc[i][2] += a * w.z; acc[i][3] += a * w.w;
    }
  }
#pragma unroll
  for (int i = 0; i < 4; i++) {
    sh[tr + i][tc + 0] = fmaxf(acc[i][0], 0.f);
    sh[tr + i][tc + 1] = fmaxf(acc[i][1], 0.f);
    sh[tr + i][tc + 2] = fmaxf(acc[i][2], 0.f);
    sh[tr + i][tc + 3] = fmaxf(acc[i][3], 0.f);
  }
  __syncthreads();
#pragma unroll
  for (int i = 0; i < 4; i++) acc[i][0] = acc[i][1] = acc[i][2] = acc[i][3] = 0.f;
#pragma unroll 8
  for (int k = 0; k < DIM; k++) {
    float4 w = *(const float4*)&sWc[k][tc];
#pragma unroll
    for (int i = 0; i < 4; i++) {
      float a = sh[tr + i][k];
      acc[i][0] += a * w.x; acc[i][1] += a * w.y;
      acc[i][2] += a * w.z; acc[i][3] += a * w.w;
    }
  }
#pragma unroll
  for (int i = 0; i < 4; i++) {
    int row = row0 + tr + i;
    if (row < N_NODES)
      *(float4*)&hw[(size_t)row * DIM + tc] =
          make_float4(acc[i][0], acc[i][1], acc[i][2], acc[i][3]);
  }
}

// ------- block 0: exclusive scan (+dinv, sentinel); block 1: WT + gcur ----
__global__ __launch_bounds__(1024) void k_scan(int* __restrict__ cnt,
    float* __restrict__ dinv, const float* __restrict__ Wih,
    const float* __restrict__ Whh, float* __restrict__ WT,
    int* __restrict__ gcur) {
  int t = threadIdx.x;
  if (blockIdx.x == 1) {  // weight transpose + bucket cursor init
    for (int i = t; i < 3 * DIM * 4 * DIM; i += 1024) {
      int k = i >> 8, tt = i & 255;
      WT[i] = (k < 2 * DIM) ? Wih[tt * 2 * DIM + k] : Whh[tt * DIM + (k - 2 * DIM)];
    }
    if (t < NB) gcur[t] = t * CAP;
    return;
  }
  __shared__ int wsums[16];
  __shared__ int carry;
  int lane = t & 63, w = t >> 6;
  if (t == 0) carry = 0;
  __syncthreads();
  for (int base = 0; base < N_NODES; base += 8192) {
    int i0 = base + t * 8;
    int v[8];
    int local = 0;
#pragma unroll
    for (int k = 0; k < 8; k++) {
      int i = i0 + k;
      v[k] = (i < N_NODES) ? cnt[i] : 0;
      local += v[k];
    }
    int x = local;
#pragma unroll
    for (int d = 1; d < 64; d <<= 1) {
      int y = __shfl_up(x, d, 64);
      if (lane >= d) x += y;
    }
    if (lane == 63) wsums[w] = x;
    __syncthreads();
    if (t < 16) {
      int y = wsums[t];
#pragma unroll
      for (int d = 1; d < 16; d <<= 1) {
        int z = __shfl_up(y, d, 64);
        if (t >= d) y += z;
      }
      wsums[t] = y;
    }
    __syncthreads();
    int excl = x - local + ((w > 0) ? wsums[w - 1] : 0) + carry;
#pragma unroll
    for (int k = 0; k < 8; k++) {
      int i = i0 + k;
      if (i < N_NODES) {
        cnt[i] = excl;
        dinv[i] = rsqrtf((float)(v[k] + 1));
        excl += v[k];
      }
    }
    __syncthreads();
    if (t == 0) carry += wsums[15];
    __syncthreads();
  }
  if (t == 0) cnt[N_NODES] = N_EDGES;  // sentinel
}

// ---------------- CSR pass 1: bin edges into NB coarse buckets ------------
__global__ __launch_bounds__(256) void k_bin(const int* __restrict__ ei,
    int* __restrict__ gcur, uint2* __restrict__ pairs) {
  __shared__ int lcnt[NB];
  __shared__ int lbase[NB];
  int t = threadIdx.x;
  int base = blockIdx.x * 2048;
  for (int i = t; i < NB; i += 256) lcnt[i] = 0;
  __syncthreads();
  int rows[8], cols[8], rank[8];
#pragma unroll
  for (int k = 0; k < 8; k++) {
    int e = base + k * 256 + t;
    if (e < N_EDGES) {
      rows[k] = ei[e];
      cols[k] = ei[N_EDGES + e];
      rank[k] = atomicAdd(&lcnt[cols[k] >> 9], 1);
    } else {
      cols[k] = -1;
    }
  }
  __syncthreads();
  for (int i = t; i < NB; i += 256) lbase[i] = atomicAdd(&gcur[i], lcnt[i]);
  __syncthreads();
#pragma unroll
  for (int k = 0; k < 8; k++) {
    if (cols[k] >= 0) {
      int b = cols[k] >> 9;
      int pos = lbase[b] + rank[k];
      if (pos < (b + 1) * CAP)
        pairs[pos] = make_uint2((unsigned)rows[k], (unsigned)cols[k]);
    }
  }
}

// ---------------- CSR pass 2: per-bucket fill (LDS cursors) ---------------
__global__ __launch_bounds__(256) void k_fill2(const uint2* __restrict__ pairs,
    const int* __restrict__ gcur, const int* __restrict__ cnt,
    int* __restrict__ adj) {
  __shared__ int lcur[NPB];
  int b = blockIdx.x, t = threadIdx.x;
  int nb0 = b * NPB;
  for (int i = t; i < NPB; i += 256) {
    int node = nb0 + i;
    lcur[i] = (node < N_NODES) ? cnt[node] : 0;
  }
  __syncthreads();
  int ne = gcur[b] - b * CAP;
  if (ne > CAP) ne = CAP;
  for (int i = t; i < ne; i += 256) {
    uint2 p = pairs[(size_t)b * CAP + i];
    int slot = atomicAdd(&lcur[p.y - nb0], 1);
    adj[slot] = (int)p.x;
  }
}

// ---------------- GCN aggregate: gather per node (one wave per node) ------
__global__ __launch_bounds__(256) void k_gather(const int* __restrict__ adj,
    const int* __restrict__ cnt, const float* __restrict__ hw,
    const float* __restrict__ dinv, const float* __restrict__ bc,
    float* __restrict__ h) {
  int node = blockIdx.x * 4 + (threadIdx.x >> 6);
  int lane = threadIdx.x & 63;
  if (node >= N_NODES) return;
  int s = cnt[node], eend = cnt[node + 1];
  float di = dinv[node];
  float acc = di * hw[(size_t)node * DIM + lane];  // self loop
  for (int cb = s; cb < eend; cb += 64) {
    int cn = min(64, eend - cb);
    int idx = (lane < cn) ? adj[cb + lane] : 0;
    float dv = (lane < cn) ? dinv[idx] : 0.f;
    float a0 = 0.f, a1 = 0.f, a2 = 0.f, a3 = 0.f;
    float a4 = 0.f, a5 = 0.f, a6 = 0.f, a7 = 0.f;
    int j = 0;
    for (; j + 8 <= cn; j += 8) {
      int r0 = __shfl(idx, j, 64), r1 = __shfl(idx, j + 1, 64);
      int r2 = __shfl(idx, j + 2, 64), r3 = __shfl(idx, j + 3, 64);
      int r4 = __shfl(idx, j + 4, 64), r5 = __shfl(idx, j + 5, 64);
      int r6 = __shfl(idx, j + 6, 64), r7 = __shfl(idx, j + 7, 64);
      float d0 = __shfl(dv, j, 64), d1 = __shfl(dv, j + 1, 64);
      float d2 = __shfl(dv, j + 2, 64), d3 = __shfl(dv, j + 3, 64);
      float d4 = __shfl(dv, j + 4, 64), d5 = __shfl(dv, j + 5, 64);
      float d6 = __shfl(dv, j + 6, 64), d7 = __shfl(dv, j + 7, 64);
      a0 += d0 * hw[(size_t)r0 * DIM + lane];
      a1 += d1 * hw[(size_t)r1 * DIM + lane];
      a2 += d2 * hw[(size_t)r2 * DIM + lane];
      a3 += d3 * hw[(size_t)r3 * DIM + lane];
      a4 += d4 * hw[(size_t)r4 * DIM + lane];
      a5 += d5 * hw[(size_t)r5 * DIM + lane];
      a6 += d6 * hw[(size_t)r6 * DIM + lane];
      a7 += d7 * hw[(size_t)r7 * DIM + lane];
    }
    for (; j < cn; j++) {
      int r = __shfl(idx, j, 64);
      float dr = __shfl(dv, j, 64);
      a0 += dr * hw[(size_t)r * DIM + lane];
    }
    acc += ((a0 + a1) + (a2 + a3)) + ((a4 + a5) + (a6 + a7));
  }
  h[(size_t)node * DIM + lane] = fmaxf(acc * di + bc[lane], 0.f);
}

// ---------------- fused Set2Set: 3x(LSTM + segment-softmax) + MLP head ----
// Attention: single pass over h, per-wave online softmax, h row reused in
// registers for the weighted accumulation. No in-loop barriers.
__global__ __launch_bounds__(256) void k_set2set(
    const float* __restrict__ h, const int* __restrict__ batch,
    const float* __restrict__ WT, const float* __restrict__ bih,
    const float* __restrict__ bhh, const float* __restrict__ W1,
    const float* __restrict__ b1, const float* __restrict__ W2,
    const float* __restrict__ b2, float* __restrict__ out) {
  int b = blockIdx.x, t = threadIdx.x;
  int wave = t >> 6, lane = t & 63;
  __shared__ float qs[2 * DIM];
  __shared__ float hsl[DIM], csl[DIM];
  __shared__ float gates[4 * DIM];
  __shared__ float red[4 * DIM];
  __shared__ float lred[4], wmax[4];
  __shared__ int seg[2];
  if (t < 2) {  // graph boundary via binary search on sorted batch
    int g = b + t;
    int lo = 0, hi = N_NODES;
    if (g == NGRAPH) lo = N_NODES;
    else while (lo < hi) { int mid = (lo + hi) >> 1; if (batch[mid] < g) lo = mid + 1; else hi = mid; }
    seg[t] = lo;
  }
  if (t < 2 * DIM) qs[t] = 0.f;
  if (t < DIM) { hsl[t] = 0.f; csl[t] = 0.f; }
  __syncthreads();
  int s = seg[0], eend = seg[1];
  float bsum = bih[t] + bhh[t];
  for (int step = 0; step < 3; step++) {
    // ---- LSTM cell: thread t computes gate t (coalesced WT reads) ----
    float g = bsum;
    if (step > 0) {  // step 0: q_star = hs = 0 -> matmul contributes nothing
      const float* wp = WT + t;
      float g1 = 0.f;
#pragma unroll 8
      for (int k = 0; k < 2 * DIM; k += 2) {
        g += qs[k] * wp[k * 4 * DIM];
        g1 += qs[k + 1] * wp[(k + 1) * 4 * DIM];
      }
#pragma unroll 8
      for (int k = 0; k < DIM; k += 2) {
        g += hsl[k] * wp[(2 * DIM + k) * 4 * DIM];
        g1 += hsl[k + 1] * wp[(2 * DIM + k + 1) * 4 * DIM];
      }
      g += g1;
    }
    gates[t] = g;
    __syncthreads();
    if (t < DIM) {
      float ig = sigmoidf(gates[t]);
      float fg = sigmoidf(gates[DIM + t]);
      float gg = tanhf(gates[2 * DIM + t]);
      float og = sigmoidf(gates[3 * DIM + t]);
      float c = fg * csl[t] + ig * gg;
      csl[t] = c;
      float hh = og * tanhf(c);
      hsl[t] = hh;
      qs[t] = hh;  // q half of q_star
    }
    __syncthreads();
    // ---- single-pass online softmax, per-wave state ----
    float q = hsl[lane];
    float m_w = -INFINITY, l_w = 0.f, racc = 0.f;
    for (int j = s + wave; j < eend; j += 4) {
      float hv = h[(size_t)j * DIM + lane];
      float p = wsum(hv * q);                 // lane-uniform score
      float m_new = fmaxf(m_w, p);
      float scale = __expf(m_w - m_new);      // first row: exp(-inf)=0
      float a = __expf(p - m_new);
      racc = racc * scale + a * hv;
      l_w = l_w * scale + a;
      m_w = m_new;
    }
    red[wave * DIM + lane] = racc;
    if (lane == 0) { lred[wave] = l_w; wmax[wave] = m_w; }
    __syncthreads();
    if (t < DIM) {
      float m_b = fmaxf(fmaxf(wmax[0], wmax[1]), fmaxf(wmax[2], wmax[3]));
      float e0 = __expf(wmax[0] - m_b), e1 = __expf(wmax[1] - m_b);
      float e2 = __expf(wmax[2] - m_b), e3 = __expf(wmax[3] - m_b);
      float r = red[t] * e0 + red[DIM + t] * e1 + red[2 * DIM + t] * e2 + red[3 * DIM + t] * e3;
      float l = lred[0] * e0 + lred[1] * e1 + lred[2] * e2 + lred[3] * e3;
      qs[DIM + t] = (l > 0.f) ? r / l : 0.f;
    }
    __syncthreads();
  }
  // ---- output MLP head ----
  if (t < DIM) {
    float acc = b1[t];
#pragma unroll
    for (int k = 0; k < 2 * DIM; k++) acc += qs[k] * W1[k * DIM + t];
    acc = fmaxf(acc, 0.f);
    float v = wsum(acc * W2[t]);
    if (t == 0) out[b] = v + b2[0];
  }
}

extern "C" void kernel_launch(void* const* d_in, const int* in_sizes, int n_in,
                              void* d_out, int out_size, void* d_ws, size_t ws_size,
                              hipStream_t stream) {
  const float* x    = (const float*)d_in[0];
  const int*   ei   = (const int*)d_in[1];
  const int*   batch= (const int*)d_in[2];
  const float* W0   = (const float*)d_in[3];
  const float* b0   = (const float*)d_in[4];
  const float* Wc   = (const float*)d_in[5];
  const float* bc   = (const float*)d_in[6];
  const float* Wih  = (const float*)d_in[7];
  const float* Whh  = (const float*)d_in[8];
  const float* bih  = (const float*)d_in[9];
  const float* bhh  = (const float*)d_in[10];
  const float* W1   = (const float*)d_in[11];
  const float* b1   = (const float*)d_in[12];
  const float* W2   = (const float*)d_in[13];
  const float* b2   = (const float*)d_in[14];
  float* out = (float*)d_out;

  float* ws   = (float*)d_ws;
  float* hw   = ws;                              // N*DIM
  float* h    = hw + (size_t)N_NODES * DIM;      // N*DIM
  float* dinv = h + (size_t)N_NODES * DIM;       // N
  float* WT   = dinv + N_NODES;                  // 192*256
  int* cnt    = (int*)(WT + 3 * DIM * 4 * DIM);  // N+2 (offsets + sentinel + pad)
  int* adj    = cnt + N_NODES + 2;               // N_EDGES
  int* gcur   = adj + N_EDGES;                   // NB bucket cursors
  uint2* pairs = (uint2*)(gcur + NB);            // NB*CAP pairs (~9.6 MB)

  hipMemsetAsync(cnt, 0, N_NODES * sizeof(int), stream);
  k_lin0cnt<<<NLIN + NCNT, 256, 0, stream>>>(x, W0, b0, Wc, hw, ei, cnt);
  k_scan<<<2, 1024, 0, stream>>>(cnt, dinv, Wih, Whh, WT, gcur);
  k_bin<<<(N_EDGES + 2047) / 2048, 256, 0, stream>>>(ei, gcur, pairs);
  k_fill2<<<NB, 256, 0, stream>>>(pairs, gcur, cnt, adj);
  k_gather<<<(N_NODES + 3) / 4, 256, 0, stream>>>(adj, cnt, hw, dinv, bc, h);
  k_set2set<<<NGRAPH, 256, 0, stream>>>(h, batch, WT, bih, bhh, W1, b1, W2, b2, out);
}

// Round 9
// 235.683 us; speedup vs baseline: 1.7540x; 1.1187x over previous
//
#include <hip/hip_runtime.h>
#include <math.h>

#define N_NODES 50000
#define N_EDGES 800000
#define NGRAPH  1024
#define IN_DIM  25
#define DIM     64

// CSR binning params
#define NPB 512                    // nodes per bucket (2^9)
#define NB  98                     // ceil(N_NODES / NPB)
#define CAP 12288                  // pairs capacity per bucket (mean 8192, ~45 sigma)

// fused grid split
#define NLIN 782                   // ceil(N_NODES / 64)
#define NBIN 391                   // ceil(N_EDGES / 2048)

__device__ inline float wsum(float v) {
#pragma unroll
  for (int off = 32; off > 0; off >>= 1) v += __shfl_xor(v, off, 64);
  return v;
}
__device__ inline float sigmoidf(float x) { return 1.f / (1.f + expf(-x)); }

// ---- fused: lin0+relu+@Wc | edge binning | LSTM weight transpose ---------
__global__ __launch_bounds__(256) void k_lin0bin(const float* __restrict__ x,
    const float* __restrict__ W0, const float* __restrict__ b0,
    const float* __restrict__ Wc, float* __restrict__ hw,
    const int* __restrict__ ei, int* __restrict__ gcur,
    uint2* __restrict__ pairs, const float* __restrict__ Wih,
    const float* __restrict__ Whh, float* __restrict__ WT) {
  __shared__ float sx[64][IN_DIM + 1];
  __shared__ float sW0[IN_DIM][DIM];
  __shared__ float sh[64][DIM + 4];
  __shared__ float sWc[DIM][DIM];
  __shared__ int lcnt[NB];
  __shared__ int lbase[NB];
  int t = threadIdx.x;
  if (blockIdx.x >= NLIN) {
    int bb = blockIdx.x - NLIN;
    if (bb == NBIN) {  // ---- LSTM weight transpose: WT[k][gate] ----
      for (int i = t; i < 3 * DIM * 4 * DIM; i += 256) {
        int k = i >> 8, tt = i & 255;
        WT[i] = (k < 2 * DIM) ? Wih[tt * 2 * DIM + k] : Whh[tt * DIM + (k - 2 * DIM)];
      }
      return;
    }
    // ---- bin branch: 2048 edges per block into NB dst-buckets ----
    int base = bb * 2048;
    for (int i = t; i < NB; i += 256) lcnt[i] = 0;
    __syncthreads();
    int rows[8], cols[8], rank[8];
#pragma unroll
    for (int k = 0; k < 8; k++) {
      int e = base + k * 256 + t;
      if (e < N_EDGES) {
        rows[k] = ei[e];
        cols[k] = ei[N_EDGES + e];
        rank[k] = atomicAdd(&lcnt[cols[k] >> 9], 1);
      } else {
        cols[k] = -1;
      }
    }
    __syncthreads();
    for (int i = t; i < NB; i += 256) lbase[i] = atomicAdd(&gcur[i], lcnt[i]);
    __syncthreads();
#pragma unroll
    for (int k = 0; k < 8; k++) {
      if (cols[k] >= 0) {
        int bkt = cols[k] >> 9;
        int pos = lbase[bkt] + rank[k];
        if (pos < CAP)
          pairs[(size_t)bkt * CAP + pos] = make_uint2((unsigned)rows[k], (unsigned)cols[k]);
      }
    }
    return;
  }
  // ---- lin0 branch: LDS-tiled (x@W0+b0).relu()@Wc, 64 rows/block ----
  int row0 = blockIdx.x * 64;
  for (int i = t; i < 64 * IN_DIM; i += 256) {
    int r = i / IN_DIM, k = i - r * IN_DIM;
    int row = row0 + r;
    sx[r][k] = (row < N_NODES) ? x[row * IN_DIM + k] : 0.f;
  }
  for (int i = t; i < IN_DIM * DIM; i += 256) sW0[i >> 6][i & 63] = W0[i];
  for (int i = t; i < DIM * DIM; i += 256) sWc[i >> 6][i & 63] = Wc[i];
  __syncthreads();
  int tc = (t & 15) * 4;
  int tr = (t >> 4) * 4;
  float acc[4][4];
  {
    float4 bb = *(const float4*)&b0[tc];
#pragma unroll
    for (int i = 0; i < 4; i++) {
      acc[i][0] = bb.x; acc[i][1] = bb.y; acc[i][2] = bb.z; acc[i][3] = bb.w;
    }
  }
#pragma unroll
  for (int k = 0; k < IN_DIM; k++) {
    float4 w = *(const float4*)&sW0[k][tc];
#pragma unroll
    for (int i = 0; i < 4; i++) {
      float a = sx[tr + i][k];
      acc[i][0] += a * w.x; acc[i][1] += a * w.y;
      acc[i][2] += a * w.z; acc[i][3] += a * w.w;
    }
  }
#pragma unroll
  for (int i = 0; i < 4; i++) {
    sh[tr + i][tc + 0] = fmaxf(acc[i][0], 0.f);
    sh[tr + i][tc + 1] = fmaxf(acc[i][1], 0.f);
    sh[tr + i][tc + 2] = fmaxf(acc[i][2], 0.f);
    sh[tr + i][tc + 3] = fmaxf(acc[i][3], 0.f);
  }
  __syncthreads();
#pragma unroll
  for (int i = 0; i < 4; i++) acc[i][0] = acc[i][1] = acc[i][2] = acc[i][3] = 0.f;
#pragma unroll 8
  for (int k = 0; k < DIM; k++) {
    float4 w = *(const float4*)&sWc[k][tc];
#pragma unroll
    for (int i = 0; i < 4; i++) {
      float a = sh[tr + i][k];
      acc[i][0] += a * w.x; acc[i][1] += a * w.y;
      acc[i][2] += a * w.z; acc[i][3] += a * w.w;
    }
  }
#pragma unroll
  for (int i = 0; i < 4; i++) {
    int row = row0 + tr + i;
    if (row < N_NODES)
      *(float4*)&hw[(size_t)row * DIM + tc] =
          make_float4(acc[i][0], acc[i][1], acc[i][2], acc[i][3]);
  }
}

// ---- per-bucket CSR: histogram -> dinv -> local scan (+base) -> fill -----
// No global atomics; all counting in LDS. cnt gets ABSOLUTE offsets.
__global__ __launch_bounds__(256) void k_fillcsr(const uint2* __restrict__ pairs,
    const int* __restrict__ gcur, int* __restrict__ cnt,
    float* __restrict__ dinv, int* __restrict__ adj) {
  __shared__ int hist[NPB];
  __shared__ int sbase;
  int b = blockIdx.x, t = threadIdx.x;
  int nb0 = b * NPB;
  for (int i = t; i < NPB; i += 256) hist[i] = 0;
  __syncthreads();
  int ne = min(gcur[b], CAP);
  const uint2* pp = pairs + (size_t)b * CAP;
  for (int i = t; i < ne; i += 256) atomicAdd(&hist[pp[i].y - nb0], 1);
  __syncthreads();
  // dinv from raw counts (+1 self loop)
  for (int i = t; i < NPB; i += 256) {
    int node = nb0 + i;
    if (node < N_NODES) dinv[node] = rsqrtf((float)(hist[i] + 1));
  }
  // bucket base = sum of gcur[j] for j < b (wave 0, register reduce)
  if (t < 64) {
    int v = 0;
    if (t < b) v += gcur[t];
    if (t + 64 < b) v += gcur[t + 64];
#pragma unroll
    for (int off = 32; off > 0; off >>= 1) v += __shfl_xor(v, off, 64);
    if (t == 0) sbase = v;
  }
  __syncthreads();
  // exclusive scan of hist in place, absolute offsets (wave 0: 8 per lane)
  if (t < 64) {
    int vv[8];
    int loc = 0;
#pragma unroll
    for (int k = 0; k < 8; k++) { vv[k] = hist[t * 8 + k]; loc += vv[k]; }
    int x = loc;
#pragma unroll
    for (int d = 1; d < 64; d <<= 1) {
      int y = __shfl_up(x, d, 64);
      if (t >= d) x += y;
    }
    int excl = sbase + x - loc;
#pragma unroll
    for (int k = 0; k < 8; k++) { hist[t * 8 + k] = excl; excl += vv[k]; }
  }
  __syncthreads();
  // write absolute CSR offsets
  for (int i = t; i < NPB; i += 256) {
    int node = nb0 + i;
    if (node < N_NODES) cnt[node] = hist[i];
  }
  if (b == NB - 1 && t == 0) cnt[N_NODES] = N_EDGES;  // sentinel
  __syncthreads();
  // fill adj via LDS cursors (absolute)
  for (int i = t; i < ne; i += 256) {
    uint2 p = pp[i];
    int slot = atomicAdd(&hist[p.y - nb0], 1);
    adj[slot] = (int)p.x;
  }
}

// ---------------- GCN aggregate: gather per node (one wave per node) ------
__global__ __launch_bounds__(256) void k_gather(const int* __restrict__ adj,
    const int* __restrict__ cnt, const float* __restrict__ hw,
    const float* __restrict__ dinv, const float* __restrict__ bc,
    float* __restrict__ h) {
  int node = blockIdx.x * 4 + (threadIdx.x >> 6);
  int lane = threadIdx.x & 63;
  if (node >= N_NODES) return;
  int s = cnt[node], eend = cnt[node + 1];
  float di = dinv[node];
  float acc = di * hw[(size_t)node * DIM + lane];  // self loop
  for (int cb = s; cb < eend; cb += 64) {
    int cn = min(64, eend - cb);
    int idx = (lane < cn) ? adj[cb + lane] : 0;
    float dv = (lane < cn) ? dinv[idx] : 0.f;
    float a0 = 0.f, a1 = 0.f, a2 = 0.f, a3 = 0.f;
    float a4 = 0.f, a5 = 0.f, a6 = 0.f, a7 = 0.f;
    int j = 0;
    for (; j + 8 <= cn; j += 8) {
      int r0 = __shfl(idx, j, 64), r1 = __shfl(idx, j + 1, 64);
      int r2 = __shfl(idx, j + 2, 64), r3 = __shfl(idx, j + 3, 64);
      int r4 = __shfl(idx, j + 4, 64), r5 = __shfl(idx, j + 5, 64);
      int r6 = __shfl(idx, j + 6, 64), r7 = __shfl(idx, j + 7, 64);
      float d0 = __shfl(dv, j, 64), d1 = __shfl(dv, j + 1, 64);
      float d2 = __shfl(dv, j + 2, 64), d3 = __shfl(dv, j + 3, 64);
      float d4 = __shfl(dv, j + 4, 64), d5 = __shfl(dv, j + 5, 64);
      float d6 = __shfl(dv, j + 6, 64), d7 = __shfl(dv, j + 7, 64);
      a0 += d0 * hw[(size_t)r0 * DIM + lane];
      a1 += d1 * hw[(size_t)r1 * DIM + lane];
      a2 += d2 * hw[(size_t)r2 * DIM + lane];
      a3 += d3 * hw[(size_t)r3 * DIM + lane];
      a4 += d4 * hw[(size_t)r4 * DIM + lane];
      a5 += d5 * hw[(size_t)r5 * DIM + lane];
      a6 += d6 * hw[(size_t)r6 * DIM + lane];
      a7 += d7 * hw[(size_t)r7 * DIM + lane];
    }
    for (; j < cn; j++) {
      int r = __shfl(idx, j, 64);
      float dr = __shfl(dv, j, 64);
      a0 += dr * hw[(size_t)r * DIM + lane];
    }
    acc += ((a0 + a1) + (a2 + a3)) + ((a4 + a5) + (a6 + a7));
  }
  h[(size_t)node * DIM + lane] = fmaxf(acc * di + bc[lane], 0.f);
}

// ---------------- fused Set2Set: 3x(LSTM + segment-softmax) + MLP head ----
__global__ __launch_bounds__(256) void k_set2set(
    const float* __restrict__ h, const int* __restrict__ batch,
    const float* __restrict__ WT, const float* __restrict__ bih,
    const float* __restrict__ bhh, const float* __restrict__ W1,
    const float* __restrict__ b1, const float* __restrict__ W2,
    const float* __restrict__ b2, float* __restrict__ out) {
  int b = blockIdx.x, t = threadIdx.x;
  int wave = t >> 6, lane = t & 63;
  __shared__ float qs[2 * DIM];
  __shared__ float hsl[DIM], csl[DIM];
  __shared__ float gates[4 * DIM];
  __shared__ float red[4 * DIM];
  __shared__ float lred[4], wmax[4];
  __shared__ int seg[2];
  if (t < 2) {  // graph boundary via binary search on sorted batch
    int g = b + t;
    int lo = 0, hi = N_NODES;
    if (g == NGRAPH) lo = N_NODES;
    else while (lo < hi) { int mid = (lo + hi) >> 1; if (batch[mid] < g) lo = mid + 1; else hi = mid; }
    seg[t] = lo;
  }
  if (t < 2 * DIM) qs[t] = 0.f;
  if (t < DIM) { hsl[t] = 0.f; csl[t] = 0.f; }
  __syncthreads();
  int s = seg[0], eend = seg[1];
  float bsum = bih[t] + bhh[t];
  for (int step = 0; step < 3; step++) {
    // ---- LSTM cell: thread t computes gate t (coalesced WT reads) ----
    float g = bsum;
    if (step > 0) {  // step 0: q_star = hs = 0 -> matmul contributes nothing
      const float* wp = WT + t;
      float g1 = 0.f;
#pragma unroll 8
      for (int k = 0; k < 2 * DIM; k += 2) {
        g += qs[k] * wp[k * 4 * DIM];
        g1 += qs[k + 1] * wp[(k + 1) * 4 * DIM];
      }
#pragma unroll 8
      for (int k = 0; k < DIM; k += 2) {
        g += hsl[k] * wp[(2 * DIM + k) * 4 * DIM];
        g1 += hsl[k + 1] * wp[(2 * DIM + k + 1) * 4 * DIM];
      }
      g += g1;
    }
    gates[t] = g;
    __syncthreads();
    if (t < DIM) {
      float ig = sigmoidf(gates[t]);
      float fg = sigmoidf(gates[DIM + t]);
      float gg = tanhf(gates[2 * DIM + t]);
      float og = sigmoidf(gates[3 * DIM + t]);
      float c = fg * csl[t] + ig * gg;
      csl[t] = c;
      float hh = og * tanhf(c);
      hsl[t] = hh;
      qs[t] = hh;  // q half of q_star
    }
    __syncthreads();
    // ---- single-pass online softmax, per-wave state ----
    float q = hsl[lane];
    float m_w = -INFINITY, l_w = 0.f, racc = 0.f;
    for (int j = s + wave; j < eend; j += 4) {
      float hv = h[(size_t)j * DIM + lane];
      float p = wsum(hv * q);                 // lane-uniform score
      float m_new = fmaxf(m_w, p);
      float scale = __expf(m_w - m_new);      // first row: exp(-inf)=0
      float a = __expf(p - m_new);
      racc = racc * scale + a * hv;
      l_w = l_w * scale + a;
      m_w = m_new;
    }
    red[wave * DIM + lane] = racc;
    if (lane == 0) { lred[wave] = l_w; wmax[wave] = m_w; }
    __syncthreads();
    if (t < DIM) {
      float m_b = fmaxf(fmaxf(wmax[0], wmax[1]), fmaxf(wmax[2], wmax[3]));
      float e0 = __expf(wmax[0] - m_b), e1 = __expf(wmax[1] - m_b);
      float e2 = __expf(wmax[2] - m_b), e3 = __expf(wmax[3] - m_b);
      float r = red[t] * e0 + red[DIM + t] * e1 + red[2 * DIM + t] * e2 + red[3 * DIM + t] * e3;
      float l = lred[0] * e0 + lred[1] * e1 + lred[2] * e2 + lred[3] * e3;
      qs[DIM + t] = (l > 0.f) ? r / l : 0.f;
    }
    __syncthreads();
  }
  // ---- output MLP head ----
  if (t < DIM) {
    float acc = b1[t];
#pragma unroll
    for (int k = 0; k < 2 * DIM; k++) acc += qs[k] * W1[k * DIM + t];
    acc = fmaxf(acc, 0.f);
    float v = wsum(acc * W2[t]);
    if (t == 0) out[b] = v + b2[0];
  }
}

extern "C" void kernel_launch(void* const* d_in, const int* in_sizes, int n_in,
                              void* d_out, int out_size, void* d_ws, size_t ws_size,
                              hipStream_t stream) {
  const float* x    = (const float*)d_in[0];
  const int*   ei   = (const int*)d_in[1];
  const int*   batch= (const int*)d_in[2];
  const float* W0   = (const float*)d_in[3];
  const float* b0   = (const float*)d_in[4];
  const float* Wc   = (const float*)d_in[5];
  const float* bc   = (const float*)d_in[6];
  const float* Wih  = (const float*)d_in[7];
  const float* Whh  = (const float*)d_in[8];
  const float* bih  = (const float*)d_in[9];
  const float* bhh  = (const float*)d_in[10];
  const float* W1   = (const float*)d_in[11];
  const float* b1   = (const float*)d_in[12];
  const float* W2   = (const float*)d_in[13];
  const float* b2   = (const float*)d_in[14];
  float* out = (float*)d_out;

  float* ws   = (float*)d_ws;
  float* hw   = ws;                              // N*DIM
  float* h    = hw + (size_t)N_NODES * DIM;      // N*DIM
  float* dinv = h + (size_t)N_NODES * DIM;       // N
  float* WT   = dinv + N_NODES;                  // 192*256
  int* cnt    = (int*)(WT + 3 * DIM * 4 * DIM);  // N+2 (absolute offsets + sentinel)
  int* adj    = cnt + N_NODES + 2;               // N_EDGES
  int* gcur   = adj + N_EDGES;                   // NB bucket counters
  uint2* pairs = (uint2*)(gcur + NB);            // NB*CAP pairs (~9.6 MB), 8B-aligned

  hipMemsetAsync(gcur, 0, NB * sizeof(int), stream);
  k_lin0bin<<<NLIN + NBIN + 1, 256, 0, stream>>>(x, W0, b0, Wc, hw, ei, gcur,
                                                 pairs, Wih, Whh, WT);
  k_fillcsr<<<NB, 256, 0, stream>>>(pairs, gcur, cnt, dinv, adj);
  k_gather<<<(N_NODES + 3) / 4, 256, 0, stream>>>(adj, cnt, hw, dinv, bc, h);
  k_set2set<<<NGRAPH, 256, 0, stream>>>(h, batch, WT, bih, bhh, W1, b1, W2, b2, out);
}